// Round 7
// baseline (407.199 us; speedup 1.0000x reference)
//
#include <hip/hip_runtime.h>
#include <hip/hip_bf16.h>

// ---------------------------------------------------------------------------
// GraphSAGE 3-layer + global mean pool, fp32 in/out.
//   layer: agg = mean_{e:dst=n} relu(h[src_e]);  h' = agg@Wl^T + bl + h@Wr^T
// R1: sorted-batch pool -> segment reduction.                 810->537us
// R2: parallel scan + wave64 agg + relu-elision.              537->449us
// R3-R5: bf16 MFMA hi/lo split GEMM (3 MFMAs, fp32-class).    449->387us
// R6: layer-2 linearity swap (gather 40-dim not 128-dim).     387->378us
// R7: edge-parallel segmented aggregation: per-node wave loop was tail-bound
//     (mean deg 12 -> unroll never ran, VALUBusy 27%). Now a block owns 32
//     nodes = one contiguous CSR edge range split evenly over 8 half-waves,
//     unroll-4 independent row loads ALWAYS in flight, register acc,
//     LDS-atomic flush at node boundaries only, coalesced mean writeback.
// ---------------------------------------------------------------------------

#define NODES 50000
#define K_DIM 128
#define N_GRAPHS 128

typedef __attribute__((ext_vector_type(8))) short short8;
typedef __attribute__((ext_vector_type(4))) short short4v;
typedef __attribute__((ext_vector_type(4))) float f32x4;

__device__ inline short f2bf(float f) {
    unsigned u = __builtin_bit_cast(unsigned, f);
    u += 0x7FFFu + ((u >> 16) & 1u);          // RNE
    return (short)(u >> 16);
}
__device__ inline float bf2f(short h) {
    unsigned u = ((unsigned)(unsigned short)h) << 16;
    return __builtin_bit_cast(float, u);
}
// pack: bits[15:0]=hi bf16, bits[31:16]=lo bf16
__device__ inline unsigned hilo_pack(float f) {
    short h = f2bf(f);
    short l = f2bf(f - bf2f(h));
    return ((unsigned)(unsigned short)h) | (((unsigned)(unsigned short)l) << 16);
}

// ---------------- CSR build ----------------
__global__ void deg_kernel(const int* __restrict__ dst, int* __restrict__ deg, int E) {
    int e = blockIdx.x * blockDim.x + threadIdx.x;
    if (e < E) atomicAdd(&deg[dst[e]], 1);
}

__global__ void scan_p1(const int* __restrict__ deg, int* __restrict__ bsum, int N) {
    int i = blockIdx.x * 256 + threadIdx.x;
    int v = (i < N) ? deg[i] : 0;
    #pragma unroll
    for (int off = 32; off > 0; off >>= 1) v += __shfl_down(v, off, 64);
    __shared__ int ws[4];
    int lane = threadIdx.x & 63, wv = threadIdx.x >> 6;
    if (lane == 0) ws[wv] = v;
    __syncthreads();
    if (threadIdx.x == 0) bsum[blockIdx.x] = ws[0] + ws[1] + ws[2] + ws[3];
}

__global__ void scan_p2(int* __restrict__ bsum, int NB) {
    int tid = threadIdx.x, lane = tid & 63, wv = tid >> 6;
    int v = (tid < NB) ? bsum[tid] : 0;
    int incl = v;
    #pragma unroll
    for (int off = 1; off < 64; off <<= 1) {
        int t = __shfl_up(incl, off, 64);
        if (lane >= off) incl += t;
    }
    __shared__ int ws[4];
    if (lane == 63) ws[wv] = incl;
    __syncthreads();
    int add = 0;
    for (int i = 0; i < wv; ++i) add += ws[i];
    incl += add;
    if (tid < NB) bsum[tid] = incl - v;
}

__global__ void scan_p3(const int* __restrict__ deg, const int* __restrict__ boff,
                        int* __restrict__ rowptr, int* __restrict__ fillpos, int N) {
    int i = blockIdx.x * 256 + threadIdx.x;
    int tid = threadIdx.x, lane = tid & 63, wv = tid >> 6;
    int v = (i < N) ? deg[i] : 0;
    int incl = v;
    #pragma unroll
    for (int off = 1; off < 64; off <<= 1) {
        int t = __shfl_up(incl, off, 64);
        if (lane >= off) incl += t;
    }
    __shared__ int ws[4];
    if (lane == 63) ws[wv] = incl;
    __syncthreads();
    int add = 0;
    for (int k = 0; k < wv; ++k) add += ws[k];
    int excl = boff[blockIdx.x] + incl + add - v;
    if (i < N) { rowptr[i] = excl; fillpos[i] = excl; }
    if (i == N) rowptr[N] = excl;
}

__global__ void fill_kernel(const int* __restrict__ src, const int* __restrict__ dst,
                            int* __restrict__ fillpos, int* __restrict__ csr_src, int E) {
    int e = blockIdx.x * blockDim.x + threadIdx.x;
    if (e < E) {
        int p = atomicAdd(&fillpos[dst[e]], 1);
        csr_src[p] = src[e];
    }
}

// ------- edge-parallel segmented aggregation (128-dim), 32 nodes/block -----
template <bool RELU>
__global__ __launch_bounds__(256) void agg_seg(const float* __restrict__ h,
                                               const int* __restrict__ rowptr,
                                               const int* __restrict__ csr_src,
                                               float* __restrict__ agg, int N) {
    constexpr int NT = 32;                    // nodes per block
    __shared__ float acc_s[NT * K_DIM];       // 16 KB
    __shared__ int rp[NT + 1];
    const int n0 = blockIdx.x * NT;
    const int tid = threadIdx.x;
    const int hw = tid >> 5;                  // half-wave 0..7
    const int l32 = tid & 31;

    if (tid <= NT) {
        int n = n0 + tid;
        rp[tid] = rowptr[n > N ? N : n];
    }
    #pragma unroll
    for (int q = tid; q < NT * K_DIM / 4; q += 256)
        reinterpret_cast<float4*>(acc_s)[q] = make_float4(0.f, 0.f, 0.f, 0.f);
    __syncthreads();

    const int e0 = rp[0], e1 = rp[NT];
    const int nE = e1 - e0;
    const int chunk = (nE + 7) >> 3;
    int i = e0 + hw * chunk;
    int iend = i + chunk; if (iend > e1) iend = e1;

    if (i < iend) {
        // find starting node j: rp[j] <= i < rp[j+1]
        int j = 0;
        while (rp[j + 1] <= i) ++j;

        float4 acc = make_float4(0.f, 0.f, 0.f, 0.f);
        auto flush = [&]() {
            float* p = &acc_s[j * K_DIM + l32 * 4];
            atomicAdd(p + 0, acc.x);
            atomicAdd(p + 1, acc.y);
            atomicAdd(p + 2, acc.z);
            atomicAdd(p + 3, acc.w);
            acc = make_float4(0.f, 0.f, 0.f, 0.f);
        };
        auto advance = [&](int idx) {
            if (idx >= rp[j + 1]) {
                flush();
                do { ++j; } while (idx >= rp[j + 1]);
            }
        };
        auto addv = [&](const float4& v) {
            if (RELU) {
                acc.x += fmaxf(v.x, 0.f); acc.y += fmaxf(v.y, 0.f);
                acc.z += fmaxf(v.z, 0.f); acc.w += fmaxf(v.w, 0.f);
            } else {
                acc.x += v.x; acc.y += v.y; acc.z += v.z; acc.w += v.w;
            }
        };

        for (; i + 3 < iend; i += 4) {
            int s0 = csr_src[i], s1 = csr_src[i + 1], s2 = csr_src[i + 2], s3 = csr_src[i + 3];
            float4 v0 = reinterpret_cast<const float4*>(h + (size_t)s0 * K_DIM)[l32];
            float4 v1 = reinterpret_cast<const float4*>(h + (size_t)s1 * K_DIM)[l32];
            float4 v2 = reinterpret_cast<const float4*>(h + (size_t)s2 * K_DIM)[l32];
            float4 v3 = reinterpret_cast<const float4*>(h + (size_t)s3 * K_DIM)[l32];
            advance(i);     addv(v0);
            advance(i + 1); addv(v1);
            advance(i + 2); addv(v2);
            advance(i + 3); addv(v3);
        }
        for (; i < iend; ++i) {
            int s0 = csr_src[i];
            float4 v0 = reinterpret_cast<const float4*>(h + (size_t)s0 * K_DIM)[l32];
            advance(i); addv(v0);
        }
        flush();
    }
    __syncthreads();

    // mean + coalesced writeback: thread t owns float4s t, t+256, ...
    #pragma unroll
    for (int q = tid; q < NT * K_DIM / 4; q += 256) {
        int node = q >> 5;                    // 32 float4 per node
        int n = n0 + node;
        if (n < N) {
            float deg = (float)(rp[node + 1] - rp[node]);
            float inv = 1.0f / fmaxf(deg, 1.0f);
            float4 v = reinterpret_cast<const float4*>(acc_s)[q];
            v.x *= inv; v.y *= inv; v.z *= inv; v.w *= inv;
            reinterpret_cast<float4*>(agg)[(size_t)n * 32 + (q & 31)] = v;
        }
    }
}

// ---------------- agg40: out[n] = mean_e yl[src_e] + yr[n] (layer 2) -------
__global__ void agg40_kernel(const float* __restrict__ yl, const float* __restrict__ yr,
                             const int* __restrict__ rowptr, const int* __restrict__ csr_src,
                             float* __restrict__ out, int N) {
    int w = (blockIdx.x * blockDim.x + threadIdx.x) >> 6;
    if (w >= N) return;
    int lane = threadIdx.x & 63;
    int s = rowptr[w], e = rowptr[w + 1];
    if (lane >= 40) return;
    float acc = 0.f;
    int i = s;
    for (; i + 3 < e; i += 4) {
        int s0 = csr_src[i], s1 = csr_src[i + 1], s2 = csr_src[i + 2], s3 = csr_src[i + 3];
        float v0 = yl[(size_t)s0 * 40 + lane];
        float v1 = yl[(size_t)s1 * 40 + lane];
        float v2 = yl[(size_t)s2 * 40 + lane];
        float v3 = yl[(size_t)s3 * 40 + lane];
        acc += (v0 + v1) + (v2 + v3);
    }
    for (; i < e; ++i) acc += yl[(size_t)csr_src[i] * 40 + lane];
    float inv = 1.0f / fmaxf((float)(e - s), 1.0f);
    out[(size_t)w * 40 + lane] = acc * inv + yr[(size_t)w * 40 + lane];
}

// ---------------- weight pre-conversion to hi/lo bf16 planes ----------------
__global__ void wconv_kernel(const float* __restrict__ w0, const float* __restrict__ w1,
                             const float* __restrict__ w2, const float* __restrict__ w3,
                             const float* __restrict__ w4, const float* __restrict__ w5,
                             short* __restrict__ whi, short* __restrict__ wlo) {
    int idx = blockIdx.x * 256 + threadIdx.x;
    const int TOT = 4 * 16384 + 2 * 6144;   // 77824
    if (idx >= TOT) return;
    float v;
    if (idx < 65536) {
        int m = idx >> 14, e = idx & 16383;
        const float* W = (m == 0) ? w0 : (m == 1) ? w1 : (m == 2) ? w2 : w3;
        v = W[e];
    } else {
        int i2 = idx - 65536;
        const float* W = (i2 < 6144) ? w4 : w5;
        int e = i2 % 6144;
        int row = e >> 7;
        v = (row < 40) ? W[e] : 0.f;
    }
    unsigned p = hilo_pack(v);
    whi[idx] = (short)(p & 0xFFFFu);
    wlo[idx] = (short)(p >> 16);
}

// ---------------- MFMA GEMM ----------------
// PHASES=2: out = A@Wl^T (+bias) + H@Wr^T;  PHASES=1: out = A@Wl^T (+bias)
template <int WAVES_M, int WAVES_N, int WM_TILES, int WN_TILES, int DOUT, bool RELU,
          int PHASES, bool BIAS>
__global__ __launch_bounds__(256) void sage_mfma(
        const float* __restrict__ A, const float* __restrict__ H,
        const short* __restrict__ Bhl, const short* __restrict__ Bll,
        const short* __restrict__ Bhr, const short* __restrict__ Blr,
        const float* __restrict__ bl, float* __restrict__ out, int N) {
    constexpr int BM = WAVES_M * WM_TILES * 16;      // 64
    constexpr int LSTR = 40;                          // shorts per LDS row (20 banks)
    const int tid = threadIdx.x;
    const int lane = tid & 63;
    const int wave = tid >> 6;
    const int wm = wave % WAVES_M;
    const int wn = wave / WAVES_M;
    const int l15 = lane & 15;
    const int quad = lane >> 4;
    const int m0 = blockIdx.x * BM;

    __shared__ __align__(16) short Ahi[BM * LSTR];
    __shared__ __align__(16) short Alo[BM * LSTR];

    f32x4 acc[WM_TILES][WN_TILES];
    #pragma unroll
    for (int i = 0; i < WM_TILES; ++i)
        #pragma unroll
        for (int j = 0; j < WN_TILES; ++j)
            acc[i][j] = (f32x4){0.f, 0.f, 0.f, 0.f};

    #pragma unroll
    for (int ph = 0; ph < PHASES; ++ph) {
        const float* __restrict__ X = ph ? H : A;
        const short* __restrict__ Bh = ph ? Bhr : Bhl;
        const short* __restrict__ Bv = ph ? Blr : Bll;
        for (int k0 = 0; k0 < K_DIM; k0 += 32) {
            __syncthreads();
            #pragma unroll
            for (int r = 0; r < BM * 8 / 256; ++r) {   // 2
                int idx = r * 256 + tid;
                int row = idx >> 3, c4 = idx & 7;
                int m = m0 + row;
                float4 v = make_float4(0.f, 0.f, 0.f, 0.f);
                if (m < N) v = *reinterpret_cast<const float4*>(X + (size_t)m * K_DIM + k0 + c4 * 4);
                unsigned px = hilo_pack(v.x);
                unsigned py = hilo_pack(v.y);
                unsigned pz = hilo_pack(v.z);
                unsigned pw = hilo_pack(v.w);
                short4v h4, l4;
                h4[0] = (short)(px & 0xFFFFu); l4[0] = (short)(px >> 16);
                h4[1] = (short)(py & 0xFFFFu); l4[1] = (short)(py >> 16);
                h4[2] = (short)(pz & 0xFFFFu); l4[2] = (short)(pz >> 16);
                h4[3] = (short)(pw & 0xFFFFu); l4[3] = (short)(pw >> 16);
                *reinterpret_cast<short4v*>(&Ahi[row * LSTR + c4 * 4]) = h4;
                *reinterpret_cast<short4v*>(&Alo[row * LSTR + c4 * 4]) = l4;
            }
            short8 bh[WN_TILES], bo[WN_TILES];
            #pragma unroll
            for (int nt = 0; nt < WN_TILES; ++nt) {
                int n = wn * WN_TILES * 16 + nt * 16 + l15;
                const short* p = Bh + (size_t)n * K_DIM + k0 + quad * 8;
                const short* q = Bv + (size_t)n * K_DIM + k0 + quad * 8;
                bh[nt] = *reinterpret_cast<const short8*>(p);
                bo[nt] = *reinterpret_cast<const short8*>(q);
            }
            __syncthreads();
            #pragma unroll
            for (int mt = 0; mt < WM_TILES; ++mt) {
                int row = wm * WM_TILES * 16 + mt * 16 + l15;
                short8 ah = *reinterpret_cast<const short8*>(&Ahi[row * LSTR + quad * 8]);
                short8 ao = *reinterpret_cast<const short8*>(&Alo[row * LSTR + quad * 8]);
                #pragma unroll
                for (int nt = 0; nt < WN_TILES; ++nt) {
                    acc[mt][nt] = __builtin_amdgcn_mfma_f32_16x16x32_bf16(ah, bh[nt], acc[mt][nt], 0, 0, 0);
                    acc[mt][nt] = __builtin_amdgcn_mfma_f32_16x16x32_bf16(ah, bo[nt], acc[mt][nt], 0, 0, 0);
                    acc[mt][nt] = __builtin_amdgcn_mfma_f32_16x16x32_bf16(ao, bh[nt], acc[mt][nt], 0, 0, 0);
                }
            }
        }
    }

    // epilogue: bias + relu + store (C/D: col=lane&15, row=quad*4+reg)
    float bias[WN_TILES];
    #pragma unroll
    for (int nt = 0; nt < WN_TILES; ++nt) {
        int col = wn * WN_TILES * 16 + nt * 16 + l15;
        bias[nt] = (BIAS && col < DOUT) ? bl[col] : 0.f;
    }
    #pragma unroll
    for (int mt = 0; mt < WM_TILES; ++mt) {
        #pragma unroll
        for (int nt = 0; nt < WN_TILES; ++nt) {
            int col = wn * WN_TILES * 16 + nt * 16 + l15;
            #pragma unroll
            for (int reg = 0; reg < 4; ++reg) {
                int row = m0 + wm * WM_TILES * 16 + mt * 16 + quad * 4 + reg;
                if (row < N && col < DOUT) {
                    float v = acc[mt][nt][reg] + bias[nt];
                    if (RELU) v = fmaxf(v, 0.f);
                    out[(size_t)row * DOUT + col] = v;
                }
            }
        }
    }
}

// ---------------- pool ----------------
__global__ void bounds_kernel(const int* __restrict__ batch, int* __restrict__ gstart, int N) {
    int g = blockIdx.x * blockDim.x + threadIdx.x;
    if (g > N_GRAPHS) return;
    int lo = 0, hi = N;
    while (lo < hi) {
        int mid = (lo + hi) >> 1;
        if (batch[mid] < g) lo = mid + 1; else hi = mid;
    }
    gstart[g] = lo;
}

__global__ __launch_bounds__(320) void pool_kernel(const float* __restrict__ h,
                                                   const int* __restrict__ gstart,
                                                   float* __restrict__ g_out) {
    int g = blockIdx.x;
    int tid = threadIdx.x;
    int c = tid % 40, r = tid / 40;
    int s = gstart[g], e = gstart[g + 1];
    float acc = 0.f;
    for (int n = s + r; n < e; n += 8)
        acc += h[(size_t)n * 40 + c];
    __shared__ float sh[8][40];
    sh[r][c] = acc;
    __syncthreads();
    if (r == 0) {
        float sum = 0.f;
        #pragma unroll
        for (int i = 0; i < 8; ++i) sum += sh[i][c];
        g_out[g * 40 + c] = sum / fmaxf((float)(e - s), 1.0f);
    }
}

extern "C" void kernel_launch(void* const* d_in, const int* in_sizes, int n_in,
                              void* d_out, int out_size, void* d_ws, size_t ws_size,
                              hipStream_t stream) {
    const float* x    = (const float*)d_in[0];
    const int*   ei   = (const int*)d_in[1];
    const int*   batch= (const int*)d_in[2];
    const float* Wl0  = (const float*)d_in[3];
    const float* bl0  = (const float*)d_in[4];
    const float* Wr0  = (const float*)d_in[5];
    const float* Wl1  = (const float*)d_in[6];
    const float* bl1  = (const float*)d_in[7];
    const float* Wr1  = (const float*)d_in[8];
    const float* Wl2  = (const float*)d_in[9];
    const float* bl2  = (const float*)d_in[10];
    const float* Wr2  = (const float*)d_in[11];

    const int N = in_sizes[0] / K_DIM;       // 50000
    const int E = in_sizes[1] / 2;           // 600000
    const int* src = ei;
    const int* dst = ei + E;

    float* out = (float*)d_out;              // h3 [N,40] then g [128,40]
    float* gsum = out + (size_t)N * 40;

    char* w = (char*)d_ws;
    auto alloc = [&](size_t bytes) {
        char* p = w;
        w += (bytes + 255) & ~(size_t)255;
        return p;
    };
    float* bufA  = (float*)alloc((size_t)N * K_DIM * 4);  // agg L0/L1; yl2/yr2 in L2
    float* bufB  = (float*)alloc((size_t)N * K_DIM * 4);  // h1
    float* bufC  = (float*)alloc((size_t)N * K_DIM * 4);  // h2
    int*   rowptr= (int*)alloc((size_t)(N + 1) * 4);
    int*   deg   = (int*)alloc((size_t)N * 4);
    int*   fillp = (int*)alloc((size_t)N * 4);
    int*   csr   = (int*)alloc((size_t)E * 4);
    int*   bsum  = (int*)alloc(256 * 4);
    int*   gstart= (int*)alloc((size_t)(N_GRAPHS + 1) * 4);
    short* whi   = (short*)alloc(77824 * 2);
    short* wlo   = (short*)alloc(77824 * 2);

    (void)hipMemsetAsync(deg, 0, (size_t)N * 4, stream);

    const int NB = (N + 255) / 256;   // 196

    // CSR build + weight conversion + pool bounds
    deg_kernel<<<(E + 255) / 256, 256, 0, stream>>>(dst, deg, E);
    scan_p1<<<NB, 256, 0, stream>>>(deg, bsum, N);
    scan_p2<<<1, 256, 0, stream>>>(bsum, NB);
    scan_p3<<<NB, 256, 0, stream>>>(deg, bsum, rowptr, fillp, N);
    fill_kernel<<<(E + 255) / 256, 256, 0, stream>>>(src, dst, fillp, csr, E);
    wconv_kernel<<<(77824 + 255) / 256, 256, 0, stream>>>(Wl0, Wr0, Wl1, Wr1, Wl2, Wr2, whi, wlo);
    bounds_kernel<<<1, 192, 0, stream>>>(batch, gstart, N);

    // weight plane offsets (shorts)
    short* hWl0 = whi;          short* lWl0 = wlo;
    short* hWr0 = whi + 16384;  short* lWr0 = wlo + 16384;
    short* hWl1 = whi + 32768;  short* lWl1 = wlo + 32768;
    short* hWr1 = whi + 49152;  short* lWr1 = wlo + 49152;
    short* hWl2 = whi + 65536;  short* lWl2 = wlo + 65536;
    short* hWr2 = whi + 71680;  short* lWr2 = wlo + 71680;

    const int segGrid  = (N + 31) / 32;       // 1563
    const int aggGrid  = (N * 64 + 255) / 256;
    const int gemmGrid = (N + 63) / 64;       // 782

    // layer 0
    agg_seg<true><<<segGrid, 256, 0, stream>>>(x, rowptr, csr, bufA, N);
    sage_mfma<1, 4, 4, 2, 128, true, 2, true><<<gemmGrid, 256, 0, stream>>>(
        bufA, x, hWl0, lWl0, hWr0, lWr0, bl0, bufB, N);
    // layer 1
    agg_seg<false><<<segGrid, 256, 0, stream>>>(bufB, rowptr, csr, bufA, N);
    sage_mfma<1, 4, 4, 2, 128, true, 2, true><<<gemmGrid, 256, 0, stream>>>(
        bufA, bufB, hWl1, lWl1, hWr1, lWr1, bl1, bufC, N);
    // layer 2 (linearity swap): yl2 = h2@Wl2^T; yr2 = h2@Wr2^T + bl2;
    //                           h3[n] = mean_e yl2[src_e] + yr2[n]
    float* yl2 = bufA;                 // N x 40
    float* yr2 = bufA + (size_t)N * 40;
    sage_mfma<4, 1, 1, 3, 40, false, 1, false><<<gemmGrid, 256, 0, stream>>>(
        bufC, bufC, hWl2, lWl2, hWl2, lWl2, bl2, yl2, N);
    sage_mfma<4, 1, 1, 3, 40, false, 1, true><<<gemmGrid, 256, 0, stream>>>(
        bufC, bufC, hWr2, lWr2, hWr2, lWr2, bl2, yr2, N);
    agg40_kernel<<<aggGrid, 256, 0, stream>>>(yl2, yr2, rowptr, csr, out, N);

    // global mean pool
    pool_kernel<<<N_GRAPHS, 320, 0, stream>>>(out, gstart, gsum);
}

// Round 8
// 403.385 us; speedup vs baseline: 1.0095x; 1.0095x over previous
//
#include <hip/hip_runtime.h>
#include <hip/hip_bf16.h>

// ---------------------------------------------------------------------------
// GraphSAGE 3-layer + global mean pool, fp32 in/out.
//   layer: agg = mean_{e:dst=n} relu(h[src_e]);  h' = agg@Wl^T + bl + h@Wr^T
// R1: sorted-batch pool -> segment reduction.                 810->537us
// R2: parallel scan + wave64 agg + relu-elision.              537->449us
// R3-R5: bf16 MFMA hi/lo split GEMM (3 MFMAs, fp32-class).    449->387us
// R6: layer-2 linearity swap (gather 40-dim not 128-dim).     387->378us
// R7: edge-parallel agg REGRESSED (57us vs 44; boundary logic serialized
//     the gather). REVERTED.                                  378->407us
// R8: (a) fuse agg INTO the L0/L1 GEMM: block=32 nodes, waves gather means
//     (proven per-node loop) directly into hi/lo A-tile LDS -> deletes
//     bufA 25.6MB write+read per layer and 2 launches. (b) layer-2: one
//     80-wide GEMM (packed [Wl2;Wr2]) instead of two 40-wide -> halves
//     A-staging there. agg40 reads the packed N x 80 buffer.
// ---------------------------------------------------------------------------

#define NODES 50000
#define K_DIM 128
#define N_GRAPHS 128

typedef __attribute__((ext_vector_type(8))) short short8;
typedef __attribute__((ext_vector_type(4))) short short4v;
typedef __attribute__((ext_vector_type(4))) float f32x4;

__device__ inline short f2bf(float f) {
    unsigned u = __builtin_bit_cast(unsigned, f);
    u += 0x7FFFu + ((u >> 16) & 1u);          // RNE
    return (short)(u >> 16);
}
__device__ inline float bf2f(short h) {
    unsigned u = ((unsigned)(unsigned short)h) << 16;
    return __builtin_bit_cast(float, u);
}
// pack: bits[15:0]=hi bf16, bits[31:16]=lo bf16
__device__ inline unsigned hilo_pack(float f) {
    short h = f2bf(f);
    short l = f2bf(f - bf2f(h));
    return ((unsigned)(unsigned short)h) | (((unsigned)(unsigned short)l) << 16);
}

// ---------------- CSR build ----------------
__global__ void deg_kernel(const int* __restrict__ dst, int* __restrict__ deg, int E) {
    int e = blockIdx.x * blockDim.x + threadIdx.x;
    if (e < E) atomicAdd(&deg[dst[e]], 1);
}

__global__ void scan_p1(const int* __restrict__ deg, int* __restrict__ bsum, int N) {
    int i = blockIdx.x * 256 + threadIdx.x;
    int v = (i < N) ? deg[i] : 0;
    #pragma unroll
    for (int off = 32; off > 0; off >>= 1) v += __shfl_down(v, off, 64);
    __shared__ int ws[4];
    int lane = threadIdx.x & 63, wv = threadIdx.x >> 6;
    if (lane == 0) ws[wv] = v;
    __syncthreads();
    if (threadIdx.x == 0) bsum[blockIdx.x] = ws[0] + ws[1] + ws[2] + ws[3];
}

__global__ void scan_p2(int* __restrict__ bsum, int NB) {
    int tid = threadIdx.x, lane = tid & 63, wv = tid >> 6;
    int v = (tid < NB) ? bsum[tid] : 0;
    int incl = v;
    #pragma unroll
    for (int off = 1; off < 64; off <<= 1) {
        int t = __shfl_up(incl, off, 64);
        if (lane >= off) incl += t;
    }
    __shared__ int ws[4];
    if (lane == 63) ws[wv] = incl;
    __syncthreads();
    int add = 0;
    for (int i = 0; i < wv; ++i) add += ws[i];
    incl += add;
    if (tid < NB) bsum[tid] = incl - v;
}

__global__ void scan_p3(const int* __restrict__ deg, const int* __restrict__ boff,
                        int* __restrict__ rowptr, int* __restrict__ fillpos, int N) {
    int i = blockIdx.x * 256 + threadIdx.x;
    int tid = threadIdx.x, lane = tid & 63, wv = tid >> 6;
    int v = (i < N) ? deg[i] : 0;
    int incl = v;
    #pragma unroll
    for (int off = 1; off < 64; off <<= 1) {
        int t = __shfl_up(incl, off, 64);
        if (lane >= off) incl += t;
    }
    __shared__ int ws[4];
    if (lane == 63) ws[wv] = incl;
    __syncthreads();
    int add = 0;
    for (int k = 0; k < wv; ++k) add += ws[k];
    int excl = boff[blockIdx.x] + incl + add - v;
    if (i < N) { rowptr[i] = excl; fillpos[i] = excl; }
    if (i == N) rowptr[N] = excl;
}

__global__ void fill_kernel(const int* __restrict__ src, const int* __restrict__ dst,
                            int* __restrict__ fillpos, int* __restrict__ csr_src, int E) {
    int e = blockIdx.x * blockDim.x + threadIdx.x;
    if (e < E) {
        int p = atomicAdd(&fillpos[dst[e]], 1);
        csr_src[p] = src[e];
    }
}

// ---------------- fused layer: out = mean-agg(relu?(h))@Wl^T + bl + h@Wr^T --
// Block = 32 nodes. Waves gather their 8 nodes' means (proven per-node loop)
// directly into full-K hi/lo A-tile in LDS, then MFMA both phases.
// Wave grid for MFMA: WAVES_M=1, WAVES_N=4 (wn=wave), WM_TILES=2, WN_TILES=2.
template <bool RELU>
__global__ __launch_bounds__(256) void fused_layer(
        const float* __restrict__ hin,
        const int* __restrict__ rowptr, const int* __restrict__ csr,
        const short* __restrict__ Bhl, const short* __restrict__ Bll,
        const short* __restrict__ Bhr, const short* __restrict__ Blr,
        const float* __restrict__ bl, float* __restrict__ out, int N) {
    constexpr int BM = 32;
    constexpr int FSTR = 136;   // full-K LDS row stride (shorts)
    constexpr int CSTR = 40;    // chunk LDS row stride (shorts)
    __shared__ __align__(16) short AhiF[BM * FSTR];
    __shared__ __align__(16) short AloF[BM * FSTR];
    __shared__ __align__(16) short Hhi[BM * CSTR];
    __shared__ __align__(16) short Hlo[BM * CSTR];
    __shared__ int rp[BM + 1];

    const int tid = threadIdx.x;
    const int lane = tid & 63;
    const int wave = tid >> 6;
    const int l15 = lane & 15;
    const int quad = lane >> 4;
    const int m0 = blockIdx.x * BM;

    if (tid <= BM) {
        int n = m0 + tid;
        rp[tid] = rowptr[n > N ? N : n];
    }
    __syncthreads();

    // ---- gather phase: wave handles local nodes wave*8 .. wave*8+7 ----
    {
        const int half = lane >> 5, l32 = lane & 31;
        for (int v = 0; v < 8; ++v) {
            int nl = wave * 8 + v;
            int s = rp[nl], e = rp[nl + 1];
            float4 acc = make_float4(0.f, 0.f, 0.f, 0.f);
            int i = s + half;
            for (; i + 2 < e; i += 4) {
                int s0 = csr[i], s1 = csr[i + 2];
                float4 v0 = reinterpret_cast<const float4*>(hin + (size_t)s0 * K_DIM)[l32];
                float4 v1 = reinterpret_cast<const float4*>(hin + (size_t)s1 * K_DIM)[l32];
                if (RELU) {
                    acc.x += fmaxf(v0.x, 0.f) + fmaxf(v1.x, 0.f);
                    acc.y += fmaxf(v0.y, 0.f) + fmaxf(v1.y, 0.f);
                    acc.z += fmaxf(v0.z, 0.f) + fmaxf(v1.z, 0.f);
                    acc.w += fmaxf(v0.w, 0.f) + fmaxf(v1.w, 0.f);
                } else {
                    acc.x += v0.x + v1.x; acc.y += v0.y + v1.y;
                    acc.z += v0.z + v1.z; acc.w += v0.w + v1.w;
                }
            }
            for (; i < e; i += 2) {
                int s0 = csr[i];
                float4 v0 = reinterpret_cast<const float4*>(hin + (size_t)s0 * K_DIM)[l32];
                if (RELU) {
                    acc.x += fmaxf(v0.x, 0.f); acc.y += fmaxf(v0.y, 0.f);
                    acc.z += fmaxf(v0.z, 0.f); acc.w += fmaxf(v0.w, 0.f);
                } else {
                    acc.x += v0.x; acc.y += v0.y; acc.z += v0.z; acc.w += v0.w;
                }
            }
            acc.x += __shfl_xor(acc.x, 32, 64);
            acc.y += __shfl_xor(acc.y, 32, 64);
            acc.z += __shfl_xor(acc.z, 32, 64);
            acc.w += __shfl_xor(acc.w, 32, 64);
            if (half == 0) {
                float inv = 1.0f / fmaxf((float)(e - s), 1.0f);
                unsigned px = hilo_pack(acc.x * inv);
                unsigned py = hilo_pack(acc.y * inv);
                unsigned pz = hilo_pack(acc.z * inv);
                unsigned pw = hilo_pack(acc.w * inv);
                short4v h4, l4;
                h4[0] = (short)(px & 0xFFFFu); l4[0] = (short)(px >> 16);
                h4[1] = (short)(py & 0xFFFFu); l4[1] = (short)(py >> 16);
                h4[2] = (short)(pz & 0xFFFFu); l4[2] = (short)(pz >> 16);
                h4[3] = (short)(pw & 0xFFFFu); l4[3] = (short)(pw >> 16);
                *reinterpret_cast<short4v*>(&AhiF[nl * FSTR + l32 * 4]) = h4;
                *reinterpret_cast<short4v*>(&AloF[nl * FSTR + l32 * 4]) = l4;
            }
        }
    }
    __syncthreads();

    f32x4 acc[2][2];
    #pragma unroll
    for (int i = 0; i < 2; ++i)
        #pragma unroll
        for (int j = 0; j < 2; ++j) acc[i][j] = (f32x4){0.f, 0.f, 0.f, 0.f};

    // ---- phase A: agg @ Wl^T (A from full-K LDS, no restaging) ----
    for (int k0 = 0; k0 < K_DIM; k0 += 32) {
        short8 bh[2], bo[2];
        #pragma unroll
        for (int nt = 0; nt < 2; ++nt) {
            int n = wave * 32 + nt * 16 + l15;
            bh[nt] = *reinterpret_cast<const short8*>(Bhl + (size_t)n * K_DIM + k0 + quad * 8);
            bo[nt] = *reinterpret_cast<const short8*>(Bll + (size_t)n * K_DIM + k0 + quad * 8);
        }
        #pragma unroll
        for (int mt = 0; mt < 2; ++mt) {
            int row = mt * 16 + l15;
            short8 ah = *reinterpret_cast<const short8*>(&AhiF[row * FSTR + k0 + quad * 8]);
            short8 ao = *reinterpret_cast<const short8*>(&AloF[row * FSTR + k0 + quad * 8]);
            #pragma unroll
            for (int nt = 0; nt < 2; ++nt) {
                acc[mt][nt] = __builtin_amdgcn_mfma_f32_16x16x32_bf16(ah, bh[nt], acc[mt][nt], 0, 0, 0);
                acc[mt][nt] = __builtin_amdgcn_mfma_f32_16x16x32_bf16(ah, bo[nt], acc[mt][nt], 0, 0, 0);
                acc[mt][nt] = __builtin_amdgcn_mfma_f32_16x16x32_bf16(ao, bh[nt], acc[mt][nt], 0, 0, 0);
            }
        }
    }

    // ---- phase B: h @ Wr^T (chunked fp32->hi/lo staging) ----
    for (int k0 = 0; k0 < K_DIM; k0 += 32) {
        __syncthreads();
        {
            int row = tid >> 3, c4 = tid & 7;   // 32 rows x 8 float4
            int m = m0 + row;
            float4 v = make_float4(0.f, 0.f, 0.f, 0.f);
            if (m < N) v = *reinterpret_cast<const float4*>(hin + (size_t)m * K_DIM + k0 + c4 * 4);
            unsigned px = hilo_pack(v.x);
            unsigned py = hilo_pack(v.y);
            unsigned pz = hilo_pack(v.z);
            unsigned pw = hilo_pack(v.w);
            short4v h4, l4;
            h4[0] = (short)(px & 0xFFFFu); l4[0] = (short)(px >> 16);
            h4[1] = (short)(py & 0xFFFFu); l4[1] = (short)(py >> 16);
            h4[2] = (short)(pz & 0xFFFFu); l4[2] = (short)(pz >> 16);
            h4[3] = (short)(pw & 0xFFFFu); l4[3] = (short)(pw >> 16);
            *reinterpret_cast<short4v*>(&Hhi[row * CSTR + c4 * 4]) = h4;
            *reinterpret_cast<short4v*>(&Hlo[row * CSTR + c4 * 4]) = l4;
        }
        __syncthreads();
        short8 bh[2], bo[2];
        #pragma unroll
        for (int nt = 0; nt < 2; ++nt) {
            int n = wave * 32 + nt * 16 + l15;
            bh[nt] = *reinterpret_cast<const short8*>(Bhr + (size_t)n * K_DIM + k0 + quad * 8);
            bo[nt] = *reinterpret_cast<const short8*>(Blr + (size_t)n * K_DIM + k0 + quad * 8);
        }
        #pragma unroll
        for (int mt = 0; mt < 2; ++mt) {
            int row = mt * 16 + l15;
            short8 ah = *reinterpret_cast<const short8*>(&Hhi[row * CSTR + quad * 8]);
            short8 ao = *reinterpret_cast<const short8*>(&Hlo[row * CSTR + quad * 8]);
            #pragma unroll
            for (int nt = 0; nt < 2; ++nt) {
                acc[mt][nt] = __builtin_amdgcn_mfma_f32_16x16x32_bf16(ah, bh[nt], acc[mt][nt], 0, 0, 0);
                acc[mt][nt] = __builtin_amdgcn_mfma_f32_16x16x32_bf16(ah, bo[nt], acc[mt][nt], 0, 0, 0);
                acc[mt][nt] = __builtin_amdgcn_mfma_f32_16x16x32_bf16(ao, bh[nt], acc[mt][nt], 0, 0, 0);
            }
        }
    }

    // ---- epilogue: bias + relu + store ----
    #pragma unroll
    for (int mt = 0; mt < 2; ++mt) {
        #pragma unroll
        for (int nt = 0; nt < 2; ++nt) {
            int col = wave * 32 + nt * 16 + l15;
            float b = bl[col];
            #pragma unroll
            for (int reg = 0; reg < 4; ++reg) {
                int row = m0 + mt * 16 + quad * 4 + reg;
                if (row < N) {
                    float v = acc[mt][nt][reg] + b;
                    v = fmaxf(v, 0.f);   // layers 0/1 always ReLU
                    out[(size_t)row * K_DIM + col] = v;
                }
            }
        }
    }
}

// ---------------- layer-2 GEMM: y80 = h2 @ [Wl2;Wr2]^T (+bl2 on cols 40-79) -
// BM=64, BN=96 (DOUT=80). WAVES_M=2 (wm=wave&1), WAVES_N=2, WM_TILES=2, WN_TILES=3.
__global__ __launch_bounds__(256) void gemm80(
        const float* __restrict__ X, const short* __restrict__ Bh,
        const short* __restrict__ Bv, const float* __restrict__ b2,
        float* __restrict__ out, int N) {
    constexpr int BM = 64;
    constexpr int LSTR = 40;
    const int tid = threadIdx.x;
    const int lane = tid & 63;
    const int wave = tid >> 6;
    const int wm = wave & 1;
    const int wn = wave >> 1;
    const int l15 = lane & 15;
    const int quad = lane >> 4;
    const int m0 = blockIdx.x * BM;

    __shared__ __align__(16) short Ahi[BM * LSTR];
    __shared__ __align__(16) short Alo[BM * LSTR];

    f32x4 acc[2][3];
    #pragma unroll
    for (int i = 0; i < 2; ++i)
        #pragma unroll
        for (int j = 0; j < 3; ++j) acc[i][j] = (f32x4){0.f, 0.f, 0.f, 0.f};

    for (int k0 = 0; k0 < K_DIM; k0 += 32) {
        __syncthreads();
        #pragma unroll
        for (int r = 0; r < 2; ++r) {
            int idx = r * 256 + tid;
            int row = idx >> 3, c4 = idx & 7;
            int m = m0 + row;
            float4 v = make_float4(0.f, 0.f, 0.f, 0.f);
            if (m < N) v = *reinterpret_cast<const float4*>(X + (size_t)m * K_DIM + k0 + c4 * 4);
            unsigned px = hilo_pack(v.x);
            unsigned py = hilo_pack(v.y);
            unsigned pz = hilo_pack(v.z);
            unsigned pw = hilo_pack(v.w);
            short4v h4, l4;
            h4[0] = (short)(px & 0xFFFFu); l4[0] = (short)(px >> 16);
            h4[1] = (short)(py & 0xFFFFu); l4[1] = (short)(py >> 16);
            h4[2] = (short)(pz & 0xFFFFu); l4[2] = (short)(pz >> 16);
            h4[3] = (short)(pw & 0xFFFFu); l4[3] = (short)(pw >> 16);
            *reinterpret_cast<short4v*>(&Ahi[row * LSTR + c4 * 4]) = h4;
            *reinterpret_cast<short4v*>(&Alo[row * LSTR + c4 * 4]) = l4;
        }
        __syncthreads();
        short8 bh[3], bo[3];
        #pragma unroll
        for (int nt = 0; nt < 3; ++nt) {
            int n = wn * 48 + nt * 16 + l15;   // < 96
            bh[nt] = *reinterpret_cast<const short8*>(Bh + (size_t)n * K_DIM + k0 + quad * 8);
            bo[nt] = *reinterpret_cast<const short8*>(Bv + (size_t)n * K_DIM + k0 + quad * 8);
        }
        #pragma unroll
        for (int mt = 0; mt < 2; ++mt) {
            int row = wm * 32 + mt * 16 + l15;
            short8 ah = *reinterpret_cast<const short8*>(&Ahi[row * LSTR + quad * 8]);
            short8 ao = *reinterpret_cast<const short8*>(&Alo[row * LSTR + quad * 8]);
            #pragma unroll
            for (int nt = 0; nt < 3; ++nt) {
                acc[mt][nt] = __builtin_amdgcn_mfma_f32_16x16x32_bf16(ah, bh[nt], acc[mt][nt], 0, 0, 0);
                acc[mt][nt] = __builtin_amdgcn_mfma_f32_16x16x32_bf16(ah, bo[nt], acc[mt][nt], 0, 0, 0);
                acc[mt][nt] = __builtin_amdgcn_mfma_f32_16x16x32_bf16(ao, bh[nt], acc[mt][nt], 0, 0, 0);
            }
        }
    }

    #pragma unroll
    for (int mt = 0; mt < 2; ++mt) {
        #pragma unroll
        for (int nt = 0; nt < 3; ++nt) {
            int col = wn * 48 + nt * 16 + l15;
            float b = (col >= 40 && col < 80) ? b2[col - 40] : 0.f;
            #pragma unroll
            for (int reg = 0; reg < 4; ++reg) {
                int row = m0 + wm * 32 + mt * 16 + quad * 4 + reg;
                if (row < N && col < 80) {
                    out[(size_t)row * 80 + col] = acc[mt][nt][reg] + b;
                }
            }
        }
    }
}

// ---------------- agg40: out[n] = mean_e yl[src_e] + yr[n] ----------------
// y80 packed: cols 0-39 = yl (h2@Wl2^T), cols 40-79 = yr (h2@Wr2^T + bl2)
__global__ void agg40_kernel(const float* __restrict__ y80,
                             const int* __restrict__ rowptr, const int* __restrict__ csr_src,
                             float* __restrict__ out, int N) {
    int w = (blockIdx.x * blockDim.x + threadIdx.x) >> 6;
    if (w >= N) return;
    int lane = threadIdx.x & 63;
    int s = rowptr[w], e = rowptr[w + 1];
    if (lane >= 40) return;
    float acc = 0.f;
    int i = s;
    for (; i + 3 < e; i += 4) {
        int s0 = csr_src[i], s1 = csr_src[i + 1], s2 = csr_src[i + 2], s3 = csr_src[i + 3];
        float v0 = y80[(size_t)s0 * 80 + lane];
        float v1 = y80[(size_t)s1 * 80 + lane];
        float v2 = y80[(size_t)s2 * 80 + lane];
        float v3 = y80[(size_t)s3 * 80 + lane];
        acc += (v0 + v1) + (v2 + v3);
    }
    for (; i < e; ++i) acc += y80[(size_t)csr_src[i] * 80 + lane];
    float inv = 1.0f / fmaxf((float)(e - s), 1.0f);
    out[(size_t)w * 40 + lane] = acc * inv + y80[(size_t)w * 80 + 40 + lane];
}

// ---------------- weight pre-conversion to hi/lo bf16 planes ----------------
// shorts: Wl0:0 Wr0:16384 Wl1:32768 Wr1:49152, W2pack(96 rows: Wl2,Wr2,zeros):65536
__global__ void wconv_kernel(const float* __restrict__ w0, const float* __restrict__ w1,
                             const float* __restrict__ w2, const float* __restrict__ w3,
                             const float* __restrict__ w4, const float* __restrict__ w5,
                             short* __restrict__ whi, short* __restrict__ wlo) {
    int idx = blockIdx.x * 256 + threadIdx.x;
    const int TOT = 4 * 16384 + 96 * 128;   // 77824
    if (idx >= TOT) return;
    float v;
    if (idx < 65536) {
        int m = idx >> 14, e = idx & 16383;
        const float* W = (m == 0) ? w0 : (m == 1) ? w1 : (m == 2) ? w2 : w3;
        v = W[e];
    } else {
        int i2 = idx - 65536;
        int row = i2 >> 7, col = i2 & 127;
        if (row < 40)      v = w4[row * 128 + col];
        else if (row < 80) v = w5[(row - 40) * 128 + col];
        else               v = 0.f;
    }
    unsigned p = hilo_pack(v);
    whi[idx] = (short)(p & 0xFFFFu);
    wlo[idx] = (short)(p >> 16);
}

// ---------------- pool ----------------
__global__ void bounds_kernel(const int* __restrict__ batch, int* __restrict__ gstart, int N) {
    int g = blockIdx.x * blockDim.x + threadIdx.x;
    if (g > N_GRAPHS) return;
    int lo = 0, hi = N;
    while (lo < hi) {
        int mid = (lo + hi) >> 1;
        if (batch[mid] < g) lo = mid + 1; else hi = mid;
    }
    gstart[g] = lo;
}

__global__ __launch_bounds__(320) void pool_kernel(const float* __restrict__ h,
                                                   const int* __restrict__ gstart,
                                                   float* __restrict__ g_out) {
    int g = blockIdx.x;
    int tid = threadIdx.x;
    int c = tid % 40, r = tid / 40;
    int s = gstart[g], e = gstart[g + 1];
    float acc = 0.f;
    for (int n = s + r; n < e; n += 8)
        acc += h[(size_t)n * 40 + c];
    __shared__ float sh[8][40];
    sh[r][c] = acc;
    __syncthreads();
    if (r == 0) {
        float sum = 0.f;
        #pragma unroll
        for (int i = 0; i < 8; ++i) sum += sh[i][c];
        g_out[g * 40 + c] = sum / fmaxf((float)(e - s), 1.0f);
    }
}

extern "C" void kernel_launch(void* const* d_in, const int* in_sizes, int n_in,
                              void* d_out, int out_size, void* d_ws, size_t ws_size,
                              hipStream_t stream) {
    const float* x    = (const float*)d_in[0];
    const int*   ei   = (const int*)d_in[1];
    const int*   batch= (const int*)d_in[2];
    const float* Wl0  = (const float*)d_in[3];
    const float* bl0  = (const float*)d_in[4];
    const float* Wr0  = (const float*)d_in[5];
    const float* Wl1  = (const float*)d_in[6];
    const float* bl1  = (const float*)d_in[7];
    const float* Wr1  = (const float*)d_in[8];
    const float* Wl2  = (const float*)d_in[9];
    const float* bl2  = (const float*)d_in[10];
    const float* Wr2  = (const float*)d_in[11];

    const int N = in_sizes[0] / K_DIM;       // 50000
    const int E = in_sizes[1] / 2;           // 600000
    const int* src = ei;
    const int* dst = ei + E;

    float* out = (float*)d_out;              // h3 [N,40] then g [128,40]
    float* gsum = out + (size_t)N * 40;

    char* w = (char*)d_ws;
    auto alloc = [&](size_t bytes) {
        char* p = w;
        w += (bytes + 255) & ~(size_t)255;
        return p;
    };
    float* bufB  = (float*)alloc((size_t)N * K_DIM * 4);  // h1
    float* bufC  = (float*)alloc((size_t)N * K_DIM * 4);  // h2
    float* y80   = (float*)alloc((size_t)N * 80 * 4);     // packed yl|yr
    int*   rowptr= (int*)alloc((size_t)(N + 1) * 4);
    int*   deg   = (int*)alloc((size_t)N * 4);
    int*   fillp = (int*)alloc((size_t)N * 4);
    int*   csr   = (int*)alloc((size_t)E * 4);
    int*   bsum  = (int*)alloc(256 * 4);
    int*   gstart= (int*)alloc((size_t)(N_GRAPHS + 1) * 4);
    short* whi   = (short*)alloc(77824 * 2);
    short* wlo   = (short*)alloc(77824 * 2);

    (void)hipMemsetAsync(deg, 0, (size_t)N * 4, stream);

    const int NB = (N + 255) / 256;   // 196

    // CSR build + weight conversion + pool bounds
    deg_kernel<<<(E + 255) / 256, 256, 0, stream>>>(dst, deg, E);
    scan_p1<<<NB, 256, 0, stream>>>(deg, bsum, N);
    scan_p2<<<1, 256, 0, stream>>>(bsum, NB);
    scan_p3<<<NB, 256, 0, stream>>>(deg, bsum, rowptr, fillp, N);
    fill_kernel<<<(E + 255) / 256, 256, 0, stream>>>(src, dst, fillp, csr, E);
    wconv_kernel<<<(77824 + 255) / 256, 256, 0, stream>>>(Wl0, Wr0, Wl1, Wr1, Wl2, Wr2, whi, wlo);
    bounds_kernel<<<1, 192, 0, stream>>>(batch, gstart, N);

    // weight plane offsets (shorts)
    short* hWl0 = whi;          short* lWl0 = wlo;
    short* hWr0 = whi + 16384;  short* lWr0 = wlo + 16384;
    short* hWl1 = whi + 32768;  short* lWl1 = wlo + 32768;
    short* hWr1 = whi + 49152;  short* lWr1 = wlo + 49152;
    short* hW2  = whi + 65536;  short* lW2  = wlo + 65536;

    const int fusedGrid = (N + 31) / 32;      // 1563
    const int gemmGrid  = (N + 63) / 64;      // 782
    const int aggGrid   = (N * 64 + 255) / 256;

    // layer 0 (gather from x with relu) -> h1
    fused_layer<true><<<fusedGrid, 256, 0, stream>>>(
        x, rowptr, csr, hWl0, lWl0, hWr0, lWr0, bl0, bufB, N);
    // layer 1 (h1 >= 0, no relu in gather) -> h2
    fused_layer<false><<<fusedGrid, 256, 0, stream>>>(
        bufB, rowptr, csr, hWl1, lWl1, hWr1, lWr1, bl1, bufC, N);
    // layer 2: y80 = h2 @ [Wl2;Wr2]^T (+bl2 on yr half); then agg40
    gemm80<<<gemmGrid, 256, 0, stream>>>(bufC, hW2, lW2, bl2, y80, N);
    agg40_kernel<<<aggGrid, 256, 0, stream>>>(y80, rowptr, csr, out, N);

    // global mean pool
    pool_kernel<<<N_GRAPHS, 320, 0, stream>>>(out, gstart, gsum);
}